// Round 1
// 105.313 us; speedup vs baseline: 1.0557x; 1.0557x over previous
//
#include <hip/hip_runtime.h>
#include <math.h>

// Output depends ONLY on q_params (d_in[9]), q_basis (d_in[10]), fc3_w (d_in[11]),
// fc3_b (d_in[12]). The conv/fc tower in the reference is dead code.
//
// Wave-parallel 16-amplitude state-vector sim: lane (l & 15) holds amplitude s.
// Gates act via __shfl_xor across the pair partner (xor masks < 16 stay inside
// each 16-lane replica group, so lanes 16-63 mirror lanes 0-15 and every lane
// ends up holding the final scalar result). Per 1q-gate cost: 2 shuffles + ~5
// VALU ops instead of the previous 128 fully-unrolled FMAs per gate
// (~3 KB code vs ~37 KB > L1I).

__device__ __forceinline__ float shx(float v, int m) {
    return __shfl_xor(v, m, 64);
}

__global__ void __launch_bounds__(256)
qhbc_kernel(const float* __restrict__ q_params,  // [DEPTH=2][NQ=4][3]
            const float* __restrict__ q_basis,   // [NQ=4][3]
            const float* __restrict__ fc3_w,     // [1][4]
            const float* __restrict__ fc3_b,     // [1]
            float4* __restrict__ out4,           // [B*2/4] float4
            int n4) {
    const int lane = threadIdx.x & 63;

    // state amplitude for s = lane & 15  (axis 0 of the (2,)*4 tensor is the
    // most-significant bit: qubit w <-> bit (8 >> w))
    float ax = ((lane & 15) == 0) ? 1.f : 0.f;
    float ay = 0.f;

    // RX = [[c, -is], [-is, c]]: n = c*a - i*s*ap  (same coeffs both halves)
    auto RX = [&](int m, float t) {
        float sn, cs; sincosf(0.5f * t, &sn, &cs);
        float px = shx(ax, m), py = shx(ay, m);
        float nx = cs * ax + sn * py;
        float ny = cs * ay - sn * px;
        ax = nx; ay = ny;
    };
    // RY = [[c, -s], [s, c]]: n = c*a + (±s)*ap  (lo: -s, hi: +s)
    auto RY = [&](int m, float t) {
        float sn, cs; sincosf(0.5f * t, &sn, &cs);
        float px = shx(ax, m), py = shx(ay, m);
        float ss = (lane & m) ? sn : -sn;
        float nx = cs * ax + ss * px;
        float ny = cs * ay + ss * py;
        ax = nx; ay = ny;
    };
    // RZ = diag(e^{-it/2}, e^{+it/2}) — diagonal, no shuffle.
    // lo: (c - i s)(x + i y) = (cx + sy) + i(cy - sx); hi: conjugate phase.
    auto RZ = [&](int m, float t) {
        float sn, cs; sincosf(0.5f * t, &sn, &cs);
        float sl = (lane & m) ? -sn : sn;
        float nx = cs * ax + sl * ay;
        float ny = cs * ay - sl * ax;
        ax = nx; ay = ny;
    };
    // CNOT(control mask cm, target mask tm): lanes with control bit set swap
    // with their target-flipped partner.
    auto CNOT = [&](int cm, int tm) {
        float px = shx(ax, tm), py = shx(ay, tm);
        const bool c = (lane & cm) != 0;
        ax = c ? px : ax;
        ay = c ? py : ay;
    };

#pragma unroll
    for (int w = 0; w < 4; ++w) {
        const int m = 8 >> w;
        RX(m, q_basis[w * 3 + 0]);
        RY(m, q_basis[w * 3 + 1]);
        RZ(m, q_basis[w * 3 + 2]);
    }

#pragma unroll
    for (int l = 0; l < 2; ++l) {
#pragma unroll
        for (int w = 0; w < 4; ++w) {
            const int m = 8 >> w;
            const int b = (l * 4 + w) * 3;
            RX(m, q_params[b + 0]);
            RY(m, q_params[b + 1]);
            RZ(m, q_params[b + 2]);
        }
        CNOT(8, 4);
        CNOT(4, 2);
        CNOT(2, 1);
    }

    // Z-expectations: ev_w = sum_s sign(bit (8>>w)) * |a_s|^2 ; butterfly sum
    // over the 16-lane group leaves the full sum in every lane.
    const float p = ax * ax + ay * ay;
    float e0 = (lane & 8) ? -p : p;
    float e1 = (lane & 4) ? -p : p;
    float e2 = (lane & 2) ? -p : p;
    float e3 = (lane & 1) ? -p : p;
#pragma unroll
    for (int m = 1; m < 16; m <<= 1) {
        e0 += shx(e0, m);
        e1 += shx(e1, m);
        e2 += shx(e2, m);
        e3 += shx(e3, m);
    }

    const float logit = e0 * fc3_w[0] + e1 * fc3_w[1] + e2 * fc3_w[2] +
                        e3 * fc3_w[3] + fc3_b[0];
    const float pr = 1.f / (1.f + expf(-logit));

    const int i = blockIdx.x * blockDim.x + threadIdx.x;
    if (i < n4) out4[i] = make_float4(pr, 1.f - pr, pr, 1.f - pr);
}

extern "C" void kernel_launch(void* const* d_in, const int* in_sizes, int n_in,
                              void* d_out, int out_size, void* d_ws, size_t ws_size,
                              hipStream_t stream) {
    const float* q_params = (const float*)d_in[9];   // [2,4,3]
    const float* q_basis  = (const float*)d_in[10];  // [4,3]
    const float* fc3_w    = (const float*)d_in[11];  // [1,4]
    const float* fc3_b    = (const float*)d_in[12];  // [1]
    float4* out4 = (float4*)d_out;                   // [B,2] f32 viewed as float4

    const int n4 = out_size / 4;  // 1024 rows * 2 floats / 4 = 512 float4 stores
    const int block = 256;
    const int grid = (n4 + block - 1) / block;  // 2 blocks
    qhbc_kernel<<<grid, block, 0, stream>>>(q_params, q_basis, fc3_w, fc3_b, out4, n4);
}